// Round 19
// baseline (155.252 us; speedup 1.0000x reference)
//
#include <hip/hip_runtime.h>
#include <math.h>
#include <limits.h>

#define NUM_CODES 1024
#define DIM 64
#define HW 1024
#define NPTS 65536
#define PTS 32
#define CAP 16
#define W_WINDOW 6.0e-4f   // hh-only window; validated r10-r18 (absmax 0)
#define RESQ_EPS 2.0e-5f   // >= |scalar-sum - mfma-sum| bound (~5e-6)
#define RESQ_MAX 64

using short8 = __attribute__((ext_vector_type(8))) short;
using f32x4  = __attribute__((ext_vector_type(4))) float;

// ---- numpy-exact helpers (verified rounds 2-18: absmax 0.0) ----
__device__ __forceinline__ float pairwise_sumsq64(const float* v) {
    float r[8];
#pragma unroll
    for (int j = 0; j < 8; ++j) r[j] = __fmul_rn(v[j], v[j]);
#pragma unroll
    for (int i = 8; i < 64; i += 8) {
#pragma unroll
        for (int j = 0; j < 8; ++j)
            r[j] = __fadd_rn(r[j], __fmul_rn(v[i + j], v[i + j]));
    }
    return __fadd_rn(
        __fadd_rn(__fadd_rn(r[0], r[1]), __fadd_rn(r[2], r[3])),
        __fadd_rn(__fadd_rn(r[4], r[5]), __fadd_rn(r[6], r[7])));
}

__device__ __forceinline__ float replica_d(const float* x, const float* wr,
                                           float t1, float t3k) {
    float acc = 0.0f;
#pragma unroll
    for (int j = 0; j < 64; ++j) acc = __fmaf_rn(x[j], wr[j], acc);
    return __fadd_rn(__fsub_rn(t1, __fmul_rn(2.0f, acc)), t3k);
}

__device__ __forceinline__ unsigned short bf16_rne(float v) {
    unsigned int u = __float_as_uint(v);
    return (unsigned short)((u + 0x7fffu + ((u >> 16) & 1u)) >> 16);
}

__device__ __forceinline__ float bf16_to_f32(unsigned short h) {
    return __uint_as_float(((unsigned int)h) << 16);
}

// ---- Kernel 0: prep  wneg2hi = bf16(-2*w)  + t3 (numpy-exact) ----
__global__ void vq_prep_kernel(const float* __restrict__ w,
                               unsigned short* __restrict__ wneg2hi,
                               float* __restrict__ t3) {
    int k = blockIdx.x * blockDim.x + threadIdx.x;
    if (k >= NUM_CODES) return;
    float row[64];
#pragma unroll
    for (int j = 0; j < 64; ++j) row[j] = w[k * DIM + j];
    t3[k] = pairwise_sumsq64(row);
#pragma unroll
    for (int j = 0; j < 64; ++j) wneg2hi[k * DIM + j] = bf16_rne(-2.0f * row[j]);
}

// ---- Kernel 1: SINGLE-PASS main. 256 thr = 4 waves; 32 points.
// 5-op tracker (m1/i1 + med3 m2) + slot-rescue queue; exact-replica select.
__global__ __launch_bounds__(256, 2) void vq_main_kernel(
        const float* __restrict__ z,
        const float* __restrict__ w,
        const unsigned short* __restrict__ wneg2hi,
        const float* __restrict__ t3,
        float* __restrict__ out) {
    __shared__ __align__(16) unsigned short s_xhi[PTS * 72];
    __shared__ float s_pmin[4][PTS];
    __shared__ float s_thr[PTS];
    __shared__ int s_list[PTS * CAP];
    __shared__ int s_cnt[PTS];
    __shared__ int s_best[PTS];
    __shared__ float s_wrow[PTS * 65];
    __shared__ int s_resq[RESQ_MAX];
    __shared__ int s_rescnt;

    const int tid = threadIdx.x;
    const int lane = tid & 63;
    const int wv = tid >> 6;          // 0..3
    const int n0 = blockIdx.x * PTS;
    const int b = n0 >> 10;
    const int hw0 = n0 & (HW - 1);

    if (tid < PTS) s_cnt[tid] = 0;
    if (tid == 0) s_rescnt = 0;

    // stage 32 points as bf16-hi into LDS; coalesced 32-wide global reads
    {
        int hw_off = tid & 31;
        int dbase = tid >> 5;         // 0..7
#pragma unroll
        for (int i = 0; i < 8; ++i) {
            int d = dbase + i * 8;
            float v = z[((size_t)(b * 64 + d)) * HW + hw0 + hw_off];
            s_xhi[hw_off * 72 + d] = bf16_rne(v);
        }
    }
    __syncthreads();

    const int col = lane & 15;
    const int q = lane >> 4;

    // A fragments for both point-tiles
    short8 ah0[2], ah1[2];
#pragma unroll
    for (int at = 0; at < 2; ++at) {
        int arow = at * 16 + col;
        ah0[at] = *(const short8*)&s_xhi[arow * 72 + q * 8];
        ah1[at] = *(const short8*)&s_xhi[arow * 72 + 32 + q * 8];
    }

    const int T0 = wv * 16;

    // per-slot trackers: min value+index, 2nd-min value only (med3 update)
    float m1[2][4], m2[2][4];
    int i1[2][4];
#pragma unroll
    for (int at = 0; at < 2; ++at)
#pragma unroll
        for (int r = 0; r < 4; ++r) {
            m1[at][r] = INFINITY; m2[at][r] = INFINITY; i1[at][r] = 0;
        }

    // ---- SINGLE PASS: score this wave's 256 codes, 5-op tracker ----
#pragma unroll
    for (int t = 0; t < 16; ++t) {
        int code = (T0 + t) * 16 + col;
        short8 b0 = *(const short8*)(wneg2hi + code * 64 + q * 8);
        short8 b1 = *(const short8*)(wneg2hi + code * 64 + 32 + q * 8);
        float t3v = t3[code];
        f32x4 cinit = {t3v, t3v, t3v, t3v};
#pragma unroll
        for (int at = 0; at < 2; ++at) {
            f32x4 c = cinit;
            c = __builtin_amdgcn_mfma_f32_16x16x32_bf16(ah0[at], b0, c, 0, 0, 0);
            c = __builtin_amdgcn_mfma_f32_16x16x32_bf16(ah1[at], b1, c, 0, 0, 0);
#pragma unroll
            for (int r = 0; r < 4; ++r) {
                float s = c[r];
                float m1o = m1[at][r];
                // med3: new m2 = median(s, m1_old, m2_old)
                m2[at][r] = fminf(fmaxf(s, m1o), m2[at][r]);
                m1[at][r] = fminf(s, m1o);
                i1[at][r] = (s < m1o) ? code : i1[at][r];
            }
        }
    }

    // cross-lane min (copy of m1) over the 16 col-lanes sharing each point
    {
        float red[2][4];
#pragma unroll
        for (int at = 0; at < 2; ++at)
#pragma unroll
            for (int r = 0; r < 4; ++r) red[at][r] = m1[at][r];
#pragma unroll
        for (int mask = 1; mask <= 8; mask <<= 1)
#pragma unroll
            for (int at = 0; at < 2; ++at)
#pragma unroll
                for (int r = 0; r < 4; ++r)
                    red[at][r] = fminf(red[at][r], __shfl_xor(red[at][r], mask, 64));
        if (col == 0) {
#pragma unroll
            for (int at = 0; at < 2; ++at)
#pragma unroll
                for (int r = 0; r < 4; ++r)
                    s_pmin[wv][at * 16 + q * 4 + r] = red[at][r];
        }
    }
    __syncthreads();

    if (tid < PTS) {
        float m = fminf(fminf(s_pmin[0][tid], s_pmin[1][tid]),
                        fminf(s_pmin[2][tid], s_pmin[3][tid]));
        s_thr[tid] = m + W_WINDOW;
    }
    __syncthreads();

    // ---- append slot-min candidates; flag slots needing rescue (m2<=thr) ----
#pragma unroll
    for (int at = 0; at < 2; ++at)
#pragma unroll
        for (int r = 0; r < 4; ++r) {
            int pt = at * 16 + q * 4 + r;
            float thrW = s_thr[pt];
            if (m1[at][r] <= thrW) {
                int idx = atomicAdd(&s_cnt[pt], 1);
                if (idx < CAP) s_list[pt * CAP + idx] = i1[at][r];
            }
            if (m2[at][r] <= thrW) {
                int e = atomicAdd(&s_rescnt, 1);
                if (e < RESQ_MAX) s_resq[e] = pt | (wv << 5) | (col << 7);
            }
        }
    __syncthreads();

    // ---- rescue: rescan flagged slots (16 codes) with scalar bf16 dot ----
    {
        int rc = s_rescnt;
        int rcl = rc < RESQ_MAX ? rc : RESQ_MAX;   // overflow -> full scan later
        for (int e = tid >> 4; e < rcl; e += 16) {
            int ent = s_resq[e];
            int pt = ent & 31;
            int wvv = (ent >> 5) & 3;
            int cc = (ent >> 7) & 15;
            int t = tid & 15;
            int code = wvv * 256 + t * 16 + cc;
            const unsigned short* xr = &s_xhi[pt * 72];
            const unsigned short* wr = wneg2hi + code * 64;
            float acc = t3[code];
#pragma unroll
            for (int j = 0; j < 64; ++j)
                acc = __fmaf_rn(bf16_to_f32(xr[j]), bf16_to_f32(wr[j]), acc);
            if (acc <= s_thr[pt] + RESQ_EPS) {
                int idx = atomicAdd(&s_cnt[pt], 1);
                if (idx < CAP) s_list[pt * CAP + idx] = code;
            }
        }
    }
    __syncthreads();

    // ---- selection: 8 threads/point; exact fp32 replica; lex (d,k) min ----
    {
        int pt = tid >> 3;            // 0..31
        int sl = tid & 7;             // 0..7 (contiguous lanes, same wave)
        int cnt = s_cnt[pt];
        int ovf = (cnt > CAP) || (s_rescnt > RESQ_MAX);
        int best;
        if (cnt <= 1 && !ovf) {
            best = s_list[pt * CAP];  // min always collected -> cnt >= 1
        } else {
            float x[64];
#pragma unroll
            for (int j = 0; j < 64; ++j)
                x[j] = z[((size_t)(b * 64 + j)) * HW + hw0 + pt];
            float t1 = pairwise_sumsq64(x);
            float dbest = INFINITY;
            int kbest = INT_MAX;
            if (!ovf) {
                for (int i = sl; i < cnt; i += 8) {
                    int k = s_list[pt * CAP + i];
                    float d = replica_d(x, w + (size_t)k * DIM, t1, t3[k]);
                    if (d < dbest || (d == dbest && k < kbest)) { dbest = d; kbest = k; }
                }
            } else {
                // overflow guard (P ~ 0): distributed exact full scan
                for (int k = sl; k < NUM_CODES; k += 8) {
                    float d = replica_d(x, w + (size_t)k * DIM, t1, t3[k]);
                    if (d < dbest || (d == dbest && k < kbest)) { dbest = d; kbest = k; }
                }
            }
            // 8-lane lexicographic (d, k) min == first-occurrence argmin
#pragma unroll
            for (int mask = 1; mask <= 4; mask <<= 1) {
                float od = __shfl_xor(dbest, mask, 64);
                int ok = __shfl_xor(kbest, mask, 64);
                if (od < dbest || (od == dbest && ok < kbest)) { dbest = od; kbest = ok; }
            }
            best = kbest;
        }
        if (sl == 0) s_best[pt] = best;
    }
    __syncthreads();

    // ---- stage chosen rows into LDS: float4 loads, contiguous per 8-group ----
    {
        int pt = tid >> 3;            // 0..31
        int sl = tid & 7;             // 0..7 -> consecutive float4s of the row
        int bk = s_best[pt];
        const float4* wr4 = (const float4*)(w + (size_t)bk * DIM);
#pragma unroll
        for (int i = 0; i < 2; ++i) {
            float4 v = wr4[i * 8 + sl];
            int cb = (i * 8 + sl) * 4;
            s_wrow[pt * 65 + cb + 0] = v.x;
            s_wrow[pt * 65 + cb + 1] = v.y;
            s_wrow[pt * 65 + cb + 2] = v.z;
            s_wrow[pt * 65 + cb + 3] = v.w;
        }
    }
    __syncthreads();

    // ---- output: out[b, c, hw0+pt] = row[c] from LDS, coalesced 32-wide ----
    {
        int pt = tid & 31;
        int cb = tid >> 5;            // 0..7
#pragma unroll
        for (int i = 0; i < 8; ++i) {
            int c = cb + i * 8;
            out[((size_t)(b * 64 + c)) * HW + hw0 + pt] = s_wrow[pt * 65 + c];
        }
    }
}

extern "C" void kernel_launch(void* const* d_in, const int* in_sizes, int n_in,
                              void* d_out, int out_size, void* d_ws, size_t ws_size,
                              hipStream_t stream) {
    const float* z = (const float*)d_in[0];
    const float* w = (const float*)d_in[1];
    float* out = (float*)d_out;

    unsigned short* wneg2hi = (unsigned short*)d_ws;    // 128 KB
    float* t3 = (float*)((char*)d_ws + 131072);         // 4 KB

    vq_prep_kernel<<<NUM_CODES / 256, 256, 0, stream>>>(w, wneg2hi, t3);
    vq_main_kernel<<<NPTS / PTS, 256, 0, stream>>>(z, w, wneg2hi, t3, out);
}

// Round 20
// 55.247 us; speedup vs baseline: 2.8102x; 2.8102x over previous
//
#include <hip/hip_runtime.h>
#include <math.h>
#include <limits.h>

#define NUM_CODES 1024
#define DIM 64
#define HW 1024
#define NPTS 65536
#define PTS 32
#define CAP 16
#define W_WINDOW 6.0e-4f   // hh-only window; validated r10-r19 (absmax 0)
#define RESQ_EPS 2.0e-5f   // >= |scalar-sum - mfma-sum| bound (~5e-6)
#define RESQ_MAX 64

using short8 = __attribute__((ext_vector_type(8))) short;
using f32x4  = __attribute__((ext_vector_type(4))) float;

// ---- numpy-exact helpers (verified rounds 2-19: absmax 0.0) ----
__device__ __forceinline__ float pairwise_sumsq64(const float* v) {
    float r[8];
#pragma unroll
    for (int j = 0; j < 8; ++j) r[j] = __fmul_rn(v[j], v[j]);
#pragma unroll
    for (int i = 8; i < 64; i += 8) {
#pragma unroll
        for (int j = 0; j < 8; ++j)
            r[j] = __fadd_rn(r[j], __fmul_rn(v[i + j], v[i + j]));
    }
    return __fadd_rn(
        __fadd_rn(__fadd_rn(r[0], r[1]), __fadd_rn(r[2], r[3])),
        __fadd_rn(__fadd_rn(r[4], r[5]), __fadd_rn(r[6], r[7])));
}

__device__ __forceinline__ float replica_d(const float* x, const float* wr,
                                           float t1, float t3k) {
    float acc = 0.0f;
#pragma unroll
    for (int j = 0; j < 64; ++j) acc = __fmaf_rn(x[j], wr[j], acc);
    return __fadd_rn(__fsub_rn(t1, __fmul_rn(2.0f, acc)), t3k);
}

__device__ __forceinline__ unsigned short bf16_rne(float v) {
    unsigned int u = __float_as_uint(v);
    return (unsigned short)((u + 0x7fffu + ((u >> 16) & 1u)) >> 16);
}

__device__ __forceinline__ float bf16_to_f32(unsigned short h) {
    return __uint_as_float(((unsigned int)h) << 16);
}

// ---- Kernel 0: prep  wneg2hi = bf16(-2*w)  + t3 (numpy-exact) ----
__global__ void vq_prep_kernel(const float* __restrict__ w,
                               unsigned short* __restrict__ wneg2hi,
                               float* __restrict__ t3) {
    int k = blockIdx.x * blockDim.x + threadIdx.x;
    if (k >= NUM_CODES) return;
    float row[64];
#pragma unroll
    for (int j = 0; j < 64; ++j) row[j] = w[k * DIM + j];
    t3[k] = pairwise_sumsq64(row);
#pragma unroll
    for (int j = 0; j < 64; ++j) wneg2hi[k * DIM + j] = bf16_rne(-2.0f * row[j]);
}

// ---- Kernel 1: SINGLE-PASS main. 256 thr = 4 waves; 32 points.
// 5-op tracker (m1/i1 + med3 m2) + slot-rescue queue; exact-replica select.
// unroll 4 (NOT full: r19 showed full unroll spills -> 196MB scratch, 155us).
__global__ __launch_bounds__(256, 2) void vq_main_kernel(
        const float* __restrict__ z,
        const float* __restrict__ w,
        const unsigned short* __restrict__ wneg2hi,
        const float* __restrict__ t3,
        float* __restrict__ out) {
    __shared__ __align__(16) unsigned short s_xhi[PTS * 72];
    __shared__ float s_pmin[4][PTS];
    __shared__ float s_thr[PTS];
    __shared__ int s_list[PTS * CAP];
    __shared__ int s_cnt[PTS];
    __shared__ int s_best[PTS];
    __shared__ float s_wrow[PTS * 65];
    __shared__ int s_resq[RESQ_MAX];
    __shared__ int s_rescnt;

    const int tid = threadIdx.x;
    const int lane = tid & 63;
    const int wv = tid >> 6;          // 0..3
    const int n0 = blockIdx.x * PTS;
    const int b = n0 >> 10;
    const int hw0 = n0 & (HW - 1);

    if (tid < PTS) s_cnt[tid] = 0;
    if (tid == 0) s_rescnt = 0;

    // stage 32 points as bf16-hi into LDS; coalesced 32-wide global reads
    {
        int hw_off = tid & 31;
        int dbase = tid >> 5;         // 0..7
#pragma unroll
        for (int i = 0; i < 8; ++i) {
            int d = dbase + i * 8;
            float v = z[((size_t)(b * 64 + d)) * HW + hw0 + hw_off];
            s_xhi[hw_off * 72 + d] = bf16_rne(v);
        }
    }
    __syncthreads();

    const int col = lane & 15;
    const int q = lane >> 4;

    // A fragments for both point-tiles
    short8 ah0[2], ah1[2];
#pragma unroll
    for (int at = 0; at < 2; ++at) {
        int arow = at * 16 + col;
        ah0[at] = *(const short8*)&s_xhi[arow * 72 + q * 8];
        ah1[at] = *(const short8*)&s_xhi[arow * 72 + 32 + q * 8];
    }

    const int T0 = wv * 16;

    // per-slot trackers: min value+index, 2nd-min value only (med3 update)
    float m1[2][4], m2[2][4];
    int i1[2][4];
#pragma unroll
    for (int at = 0; at < 2; ++at)
#pragma unroll
        for (int r = 0; r < 4; ++r) {
            m1[at][r] = INFINITY; m2[at][r] = INFINITY; i1[at][r] = 0;
        }

    // ---- SINGLE PASS: score this wave's 256 codes, 5-op tracker ----
#pragma unroll 4
    for (int t = 0; t < 16; ++t) {
        int code = (T0 + t) * 16 + col;
        short8 b0 = *(const short8*)(wneg2hi + code * 64 + q * 8);
        short8 b1 = *(const short8*)(wneg2hi + code * 64 + 32 + q * 8);
        float t3v = t3[code];
        f32x4 cinit = {t3v, t3v, t3v, t3v};
#pragma unroll
        for (int at = 0; at < 2; ++at) {
            f32x4 c = cinit;
            c = __builtin_amdgcn_mfma_f32_16x16x32_bf16(ah0[at], b0, c, 0, 0, 0);
            c = __builtin_amdgcn_mfma_f32_16x16x32_bf16(ah1[at], b1, c, 0, 0, 0);
#pragma unroll
            for (int r = 0; r < 4; ++r) {
                float s = c[r];
                float m1o = m1[at][r];
                // med3: new m2 = median(s, m1_old, m2_old)
                m2[at][r] = fminf(fmaxf(s, m1o), m2[at][r]);
                m1[at][r] = fminf(s, m1o);
                i1[at][r] = (s < m1o) ? code : i1[at][r];
            }
        }
    }

    // cross-lane min (copy of m1) over the 16 col-lanes sharing each point
    {
        float red[2][4];
#pragma unroll
        for (int at = 0; at < 2; ++at)
#pragma unroll
            for (int r = 0; r < 4; ++r) red[at][r] = m1[at][r];
#pragma unroll
        for (int mask = 1; mask <= 8; mask <<= 1)
#pragma unroll
            for (int at = 0; at < 2; ++at)
#pragma unroll
                for (int r = 0; r < 4; ++r)
                    red[at][r] = fminf(red[at][r], __shfl_xor(red[at][r], mask, 64));
        if (col == 0) {
#pragma unroll
            for (int at = 0; at < 2; ++at)
#pragma unroll
                for (int r = 0; r < 4; ++r)
                    s_pmin[wv][at * 16 + q * 4 + r] = red[at][r];
        }
    }
    __syncthreads();

    if (tid < PTS) {
        float m = fminf(fminf(s_pmin[0][tid], s_pmin[1][tid]),
                        fminf(s_pmin[2][tid], s_pmin[3][tid]));
        s_thr[tid] = m + W_WINDOW;
    }
    __syncthreads();

    // ---- append slot-min candidates; flag slots needing rescue (m2<=thr) ----
#pragma unroll
    for (int at = 0; at < 2; ++at)
#pragma unroll
        for (int r = 0; r < 4; ++r) {
            int pt = at * 16 + q * 4 + r;
            float thrW = s_thr[pt];
            if (m1[at][r] <= thrW) {
                int idx = atomicAdd(&s_cnt[pt], 1);
                if (idx < CAP) s_list[pt * CAP + idx] = i1[at][r];
            }
            if (m2[at][r] <= thrW) {
                int e = atomicAdd(&s_rescnt, 1);
                if (e < RESQ_MAX) s_resq[e] = pt | (wv << 5) | (col << 7);
            }
        }
    __syncthreads();

    // ---- rescue: rescan flagged slots (16 codes) with scalar bf16 dot ----
    {
        int rc = s_rescnt;
        int rcl = rc < RESQ_MAX ? rc : RESQ_MAX;   // overflow -> full scan later
        for (int e = tid >> 4; e < rcl; e += 16) {
            int ent = s_resq[e];
            int pt = ent & 31;
            int wvv = (ent >> 5) & 3;
            int cc = (ent >> 7) & 15;
            int t = tid & 15;
            int code = wvv * 256 + t * 16 + cc;
            const unsigned short* xr = &s_xhi[pt * 72];
            const unsigned short* wr = wneg2hi + code * 64;
            float acc = t3[code];
#pragma unroll
            for (int j = 0; j < 64; ++j)
                acc = __fmaf_rn(bf16_to_f32(xr[j]), bf16_to_f32(wr[j]), acc);
            if (acc <= s_thr[pt] + RESQ_EPS) {
                int idx = atomicAdd(&s_cnt[pt], 1);
                if (idx < CAP) s_list[pt * CAP + idx] = code;
            }
        }
    }
    __syncthreads();

    // ---- selection: 8 threads/point; exact fp32 replica; lex (d,k) min ----
    {
        int pt = tid >> 3;            // 0..31
        int sl = tid & 7;             // 0..7 (contiguous lanes, same wave)
        int cnt = s_cnt[pt];
        int ovf = (cnt > CAP) || (s_rescnt > RESQ_MAX);
        int best;
        if (cnt <= 1 && !ovf) {
            best = s_list[pt * CAP];  // min always collected -> cnt >= 1
        } else {
            float x[64];
#pragma unroll
            for (int j = 0; j < 64; ++j)
                x[j] = z[((size_t)(b * 64 + j)) * HW + hw0 + pt];
            float t1 = pairwise_sumsq64(x);
            float dbest = INFINITY;
            int kbest = INT_MAX;
            if (!ovf) {
                for (int i = sl; i < cnt; i += 8) {
                    int k = s_list[pt * CAP + i];
                    float d = replica_d(x, w + (size_t)k * DIM, t1, t3[k]);
                    if (d < dbest || (d == dbest && k < kbest)) { dbest = d; kbest = k; }
                }
            } else {
                // overflow guard (P ~ 0): distributed exact full scan
                for (int k = sl; k < NUM_CODES; k += 8) {
                    float d = replica_d(x, w + (size_t)k * DIM, t1, t3[k]);
                    if (d < dbest || (d == dbest && k < kbest)) { dbest = d; kbest = k; }
                }
            }
            // 8-lane lexicographic (d, k) min == first-occurrence argmin
#pragma unroll
            for (int mask = 1; mask <= 4; mask <<= 1) {
                float od = __shfl_xor(dbest, mask, 64);
                int ok = __shfl_xor(kbest, mask, 64);
                if (od < dbest || (od == dbest && ok < kbest)) { dbest = od; kbest = ok; }
            }
            best = kbest;
        }
        if (sl == 0) s_best[pt] = best;
    }
    __syncthreads();

    // ---- stage chosen rows into LDS: float4 loads, contiguous per 8-group ----
    {
        int pt = tid >> 3;            // 0..31
        int sl = tid & 7;             // 0..7 -> consecutive float4s of the row
        int bk = s_best[pt];
        const float4* wr4 = (const float4*)(w + (size_t)bk * DIM);
#pragma unroll
        for (int i = 0; i < 2; ++i) {
            float4 v = wr4[i * 8 + sl];
            int cb = (i * 8 + sl) * 4;
            s_wrow[pt * 65 + cb + 0] = v.x;
            s_wrow[pt * 65 + cb + 1] = v.y;
            s_wrow[pt * 65 + cb + 2] = v.z;
            s_wrow[pt * 65 + cb + 3] = v.w;
        }
    }
    __syncthreads();

    // ---- output: out[b, c, hw0+pt] = row[c] from LDS, coalesced 32-wide ----
    {
        int pt = tid & 31;
        int cb = tid >> 5;            // 0..7
#pragma unroll
        for (int i = 0; i < 8; ++i) {
            int c = cb + i * 8;
            out[((size_t)(b * 64 + c)) * HW + hw0 + pt] = s_wrow[pt * 65 + c];
        }
    }
}

extern "C" void kernel_launch(void* const* d_in, const int* in_sizes, int n_in,
                              void* d_out, int out_size, void* d_ws, size_t ws_size,
                              hipStream_t stream) {
    const float* z = (const float*)d_in[0];
    const float* w = (const float*)d_in[1];
    float* out = (float*)d_out;

    unsigned short* wneg2hi = (unsigned short*)d_ws;    // 128 KB
    float* t3 = (float*)((char*)d_ws + 131072);         // 4 KB

    vq_prep_kernel<<<NUM_CODES / 256, 256, 0, stream>>>(w, wneg2hi, t3);
    vq_main_kernel<<<NPTS / PTS, 256, 0, stream>>>(z, w, wneg2hi, t3, out);
}